// Round 7
// baseline (487.262 us; speedup 1.0000x reference)
//
#include <hip/hip_runtime.h>
#include <stdint.h>

// CasualSelfAttention (buggy reference preserved): B=4, S=4096, D=768, fp32 I/O
// (sniffed), bf16 MFMA internals.
// R14: persistent 4-tile EXPSUM. R13 counters: EXPSUM 143.5us with BOTH pipes
// at ~28% (MfmaUtil 29, HBM 22) -> overlap-bound, not roofline. LDS=128KB =>
// 1 block/CU => grid 1024 = 4 sequential rounds, each paying an exposed
// 7-half-tile prologue (~5us) + tail drain. Fix: grid 256 (1/CU, single
// residency), each block runs 4 output tiles (same z, same m-row, 4 consecutive
// n-panels; per-XCD footprint identical to the proven chunk map) as ONE
// seamless 48-iteration K-pipeline: the (u+1).R3/(u+2).R0-R2 stage-lookahead
// continues across tile boundaries (stage rate 4/iter unchanged => the
// counted-vmcnt(6) invariant "ph4 wait covers buf(u+1)" holds automatically).
// Epilogue runs between boundary phases: separate 4KB LDS scratch (fshx), raw
// lgkmcnt(0)+s_barrier (NOT __syncthreads - would vmcnt(0)-drain the
// prefetch). Epilogue stores over-poison the next vmcnt(6): correct (over-
// wait), ~1-2us L2-ack. group<4 falls back to the NT=1 path.
// Kept from R13: separate q/k/vT projections (fusion regresses EXPSUM, proven
// 3x), fused sniff+normalize, atomic-free lsum2, 1D XCD chunk for NT=1 grids.
// Pipeline: normalize(+sniff) -> q/k/vT projections ->
// { P=exp(q@k^T) & partial rowsums; yT = vT@P^T / l } -> y'@Wc^T+bc.

typedef __bf16 bf16;
typedef __bf16 bf16x4 __attribute__((ext_vector_type(4)));
typedef __bf16 bf16x8 __attribute__((ext_vector_type(8)));
typedef float f32x4 __attribute__((ext_vector_type(4)));

#define OFF_Q    0L
#define OFF_K    25165824L
#define OFF_VT   50331648L
#define OFF_W    75497472L
#define OFF_B    80216064L
#define OFF_FLAG 80222208L
#define OFF_L    80223232L
#define OFF_ATT  80289792L
#define ATT_B    33554432L   // one batch of p, bytes
#define SD       3145728L    // 4096*768 elements
#define KOFF     12582912L   // (OFF_K-OFF_Q) in elems
#define VTOFF    25165824L   // (OFF_VT-OFF_Q) in elems

#define M_PLAIN  0   // C = (acc + bias[col]) * alpha, row-major packed (bf16/f32 via oflag)
#define M_TRANSC 1   // C^T store, packed column bf16x4 (natural operand order)
#define M_EXPSUM 2   // C = bf16(exp(acc)); block-local partial row-sums -> lsum2[cg][row]
#define M_DIVL   3   // C = acc * (1 / sum_cg lsum2[cg][col])

__device__ __forceinline__ void glds16(const void* g, void* s) {
  __builtin_amdgcn_global_load_lds((const __attribute__((address_space(1))) void*)g,
                                   (__attribute__((address_space(3))) void*)s, 16, 0, 0);
}

#define SBAR()  do { asm volatile("" ::: "memory"); __builtin_amdgcn_s_barrier(); \
                     asm volatile("" ::: "memory"); } while (0)
#define LGKM0() do { asm volatile("s_waitcnt lgkmcnt(0)" ::: "memory"); \
                     __builtin_amdgcn_sched_barrier(0); } while (0)

// swapped order -> acc holds C^T fragment -> packed row-major stores
#define MFMA2(ac, aa, bb) do { \
  ac = __builtin_amdgcn_mfma_f32_16x16x32_bf16((bb)[0], (aa)[0], ac, 0, 0, 0); \
  ac = __builtin_amdgcn_mfma_f32_16x16x32_bf16((bb)[1], (aa)[1], ac, 0, 0, 0); \
} while (0)
// natural order -> packed transposed (column) stores
#define MFMA2T(ac, aa, bb) do { \
  ac = __builtin_amdgcn_mfma_f32_16x16x32_bf16((aa)[0], (bb)[0], ac, 0, 0, 0); \
  ac = __builtin_amdgcn_mfma_f32_16x16x32_bf16((aa)[1], (bb)[1], ac, 0, 0, 0); \
} while (0)

// MODE is a template constant -> branch folds at compile time.
#define CLUSTER(I0, JO, AF) do { \
  if (MODE == M_TRANSC) { \
    _Pragma("unroll") for (int i = 0; i < 4; ++i) \
      _Pragma("unroll") for (int j = 0; j < 2; ++j) MFMA2T(acc[(I0)+i][(JO)+j], AF[i], bF[(JO)+j]); \
  } else { \
    _Pragma("unroll") for (int i = 0; i < 4; ++i) \
      _Pragma("unroll") for (int j = 0; j < 2; ++j) MFMA2(acc[(I0)+i][(JO)+j], AF[i], bF[(JO)+j]); \
  } \
} while (0)

__device__ __forceinline__ void norm8(const void* __restrict__ src, bf16* __restrict__ dst,
                                      long i, long n8, int f)
{
  if (i >= n8) return;
  bf16x8 o;
  if (f) {
    const float4 a = ((const float4*)src)[2 * i];
    const float4 b = ((const float4*)src)[2 * i + 1];
    o[0] = (bf16)a.x; o[1] = (bf16)a.y; o[2] = (bf16)a.z; o[3] = (bf16)a.w;
    o[4] = (bf16)b.x; o[5] = (bf16)b.y; o[6] = (bf16)b.z; o[7] = (bf16)b.w;
  } else {
    o = ((const bf16x8*)src)[i];
  }
  ((bf16x8*)dst)[i] = o;
}

// One launch: per-block dtype sniff (512 u16 of x, L2-broadcast), then
// x -> xn (6144 blocks), 4x W (288 each), 4x bias (1 each).
__global__ void normalize_all(const void* x,
                              const void* w0, const void* b0, const void* w1, const void* b1,
                              const void* w2, const void* b2, const void* w3, const void* b3,
                              bf16* __restrict__ xn, bf16* __restrict__ Wn,
                              bf16* __restrict__ bn, int* __restrict__ flagOut)
{
  const int t = threadIdx.x;
  __shared__ int sflag;
  if (t == 0) sflag = 0;
  __syncthreads();
  {
    const uint16_t* xu = (const uint16_t*)x;
    const int e = (xu[2 * t] >> 7) & 0xFF;   // even u16: bf16 value / fp32 mantissa-low
    if (e >= 0xE0) sflag = 1;                // benign race, all writers store 1
  }
  __syncthreads();
  const int f = sflag;
  int b = blockIdx.x;
  if (b == 0 && t == 0) *flagOut = f;

  if (b < 6144) { norm8(x, xn, (long)b * 256 + t, 1572864L, f); return; }
  b -= 6144;
  if (b < 1152) {
    const int w = b / 288;
    const void* s = (w == 0) ? w0 : (w == 1) ? w1 : (w == 2) ? w2 : w3;
    norm8(s, Wn + (long)w * 589824L, (long)(b % 288) * 256 + t, 73728L, f);
    return;
  }
  b -= 1152;
  const void* s = (b == 0) ? b0 : (b == 1) ? b1 : (b == 2) ? b2 : b3;
  norm8(s, bn + (long)b * 768L, (long)t, 96L, f);
}

// C[m][n] = f(sum_k A[m][k]*Bm[n][k]); bf16 in, fp32 accum.
// 256x256 tile, 8 waves (2x4), BK=64, 8-phase schedule. K multiple of 64.
// NT=1: one tile per block (grid as before). NT=4: persistent block runs 4
// tiles (same z & m-row, n0+i*256) as one seamless K-pipeline; grid (256,1,1).
template <int MODE, int NT = 1>
__launch_bounds__(512, 2)
__global__ void gemm256(const bf16* __restrict__ A, int lda, long strideA,
                        const bf16* __restrict__ Bm, int ldb, long strideB,
                        void* __restrict__ Cv, int ldc, long strideC,
                        int K, const bf16* __restrict__ bias, float alpha,
                        const int* __restrict__ oflag, float* __restrict__ lsum)
{
  __shared__ bf16 lds[65536];                   // 2 bufs x 4 regions x 8192 elems
  __shared__ float fshx[(NT > 1) ? 1024 : 1];   // NT>1: epilogue scratch (LDS busy)

  long m0, n0; int zdec;
  if constexpr (NT > 1) {
    // p -> z = p>>6; within z: XCD x = p&7 owns m-rows {2x,2x+1} x all n (as
    // the proven chunk); block j=(p&63)>>3: m-row 2x+(j>>2), n-quad j&3.
    const int p = blockIdx.x;
    zdec = p >> 6;
    const int qq = p & 63, jj = qq >> 3;
    m0 = (long)(2 * (qq & 7) + (jj >> 2)) * 256;
    n0 = (long)((jj & 3) * 4) * 256;            // tiles i: n0 + i*256
  } else {
    zdec = blockIdx.z;
    // XCD-aware bijective 1D chunk (R8-proven). nwg%8==0 for all launches.
    const int gx = gridDim.x, gy = gridDim.y;
    const int lin = blockIdx.y * gx + blockIdx.x;
    const int cpx = (gx * gy) >> 3;
    const int nlin = (lin & 7) * cpx + (lin >> 3);
    m0 = (long)(nlin / gx) * 256; n0 = (long)(nlin % gx) * 256;
  }
  A  += (long)zdec * strideA;
  Bm += (long)zdec * strideB;
  // lsum = per-batch [16 colgrp][4096] f32 partial row-sums (no atomics).
  if (MODE == M_EXPSUM || MODE == M_DIVL) lsum += (long)zdec * 65536L;

  const int tid = threadIdx.x;
  const int wv = tid >> 6, lane = tid & 63;
  const int lr = lane & 15, quad = lane >> 4;
  const int wm = (wv >> 2) << 7;   // 0 / 128
  const int wn = (wv & 3) << 6;    // 0 / 64 / 128 / 192

  f32x4 acc[8][4];
  const f32x4 zero = {0.f, 0.f, 0.f, 0.f};
#pragma unroll
  for (int i = 0; i < 8; ++i)
#pragma unroll
    for (int j = 0; j < 4; ++j) acc[i][j] = zero;

  // --- staging: linear LDS dest (wave base + lane*16B), pre-swizzled global src.
  const int rowid = (wv << 4) + (lane >> 3);                // + 8 for 2nd glds
  const int colsw = ((lane & 7) ^ ((lane >> 3) & 7)) << 3;  // swizzled k-offset (elems)
  const long lda8 = 8L * lda, ldb8 = 8L * ldb;
  const bf16* paL = A + (m0 + rowid) * (long)lda + colsw;
  const bf16* paH = paL + 128L * lda;
  const bf16* pbL = Bm + (n0 + rowid) * (long)ldb + colsw;
  const bf16* pbH = pbL + 128L * ldb;

  auto STG = [&](const bf16* src, long ld8, int tbuf, int reg) {
    bf16* d = lds + (tbuf << 15) + (reg << 13) + (wv << 10);
    glds16(src, d);
    glds16(src + ld8, d + 512);
  };

  // region ids: R0=B-lo, R1=A-lo, R2=B-hi, R3=A-hi
  const int regA = 1 + ((wv >> 2) << 1);        // 1 or 3
  const int regB = wv & 2;                      // 0 or 2
  const int aoff = lr << 6;
  const int boff = ((wv & 1) << 12) + (lr << 6);
  const int xo  = (lr & 7) << 3;
  const int ok0 = (quad << 3) ^ xo;             // kk=0 swizzled read offset
  const int ok1 = (32 + (quad << 3)) ^ xo;      // kk=1

  const int ntk = K >> 6;          // K-tiles per output tile
  const int NU  = NT * ntk;        // total pipeline iterations
  const long nstep = 256L * ldb;   // B-row advance per output tile (NT>1)

  // ---- epilogue (applied per output tile at column base n0e) ----
  auto epi = [&](long n0e) {
    if constexpr (MODE == M_TRANSC) {
      // natural order: acc[i][j][r] = C[m0+wm+i*16+quad*4+r][n0e+wn+j*16+lr].
#pragma unroll
      for (int j = 0; j < 4; ++j) {
        const long col = n0e + wn + j * 16 + lr;
        const float bv = (float)bias[col];
#pragma unroll
        for (int i = 0; i < 8; ++i) {
          const long row = m0 + wm + i * 16 + quad * 4;
          bf16x4 v4;
#pragma unroll
          for (int r = 0; r < 4; ++r) v4[r] = (bf16)((acc[i][j][r] + bv) * alpha);
          *(bf16x4*)((bf16*)Cv + (long)zdec * strideC + col * (long)ldc + row) = v4;
        }
      }
      return;
    }
    // Swapped layout: acc[i][j][r] = C[m0+wm+i*16+lr][n0e+wn+j*16+quad*4+r].
    float* fsh = (NT > 1) ? fshx : (float*)lds;  // NT==1: K-loop LDS is dead

    if constexpr (MODE == M_DIVL) {
      if (tid < 256) {
        float s = 0.f;
#pragma unroll
        for (int cg = 0; cg < 16; ++cg) s += lsum[cg * 4096 + n0e + tid];
        fsh[tid] = 1.0f / s;
      }
      __syncthreads();
    }

    const int outf32 = (MODE == M_PLAIN) && (oflag != nullptr) && (*oflag != 0);
    long colb[4];
    f32x4 addv[4];   // bias (M_PLAIN) or reciprocal row-sum (M_DIVL)
#pragma unroll
    for (int j = 0; j < 4; ++j) {
      colb[j] = n0e + wn + j * 16 + quad * 4;
      if (MODE == M_PLAIN) {
        const bf16x4 bb = *(const bf16x4*)(bias + colb[j]);
#pragma unroll
        for (int r = 0; r < 4; ++r) addv[j][r] = (float)bb[r];
      } else if (MODE == M_DIVL) {
        addv[j] = *(const f32x4*)(fsh + (int)(colb[j] - n0e));
      }
    }
#pragma unroll
    for (int i = 0; i < 8; ++i) {
      const long row = m0 + wm + i * 16 + lr;
      char* rowp = (char*)Cv + ((long)zdec * strideC + row * (long)ldc) * (outf32 ? 4 : 2);
      float rsum = 0.f;
#pragma unroll
      for (int j = 0; j < 4; ++j) {
        f32x4 v;
#pragma unroll
        for (int r = 0; r < 4; ++r) {
          float t = acc[i][j][r];
          if (MODE == M_PLAIN)       t = (t + addv[j][r]) * alpha;
          else if (MODE == M_EXPSUM) t = __expf(t);
          else if (MODE == M_DIVL)   t = t * addv[j][r];
          v[r] = t;
        }
        if (MODE == M_PLAIN && outf32) {
          *(f32x4*)(rowp + colb[j] * 4) = v;
        } else {
          bf16x4 v4;
#pragma unroll
          for (int r = 0; r < 4; ++r) v4[r] = (bf16)v[r];
          if (MODE == M_EXPSUM) {
#pragma unroll
            for (int r = 0; r < 4; ++r) rsum += (float)v4[r];  // sum what PV reads
          }
          *(bf16x4*)(rowp + colb[j] * 2) = v4;
        }
      }
      if (MODE == M_EXPSUM) {
        // full 64-col strip sum for this row, per n-wave group -> LDS partial.
        rsum += __shfl_xor(rsum, 16);
        rsum += __shfl_xor(rsum, 32);
        if (quad == 0) fsh[((wm + i * 16 + lr) << 2) + (wv & 3)] = rsum;
      }
    }
    if (MODE == M_EXPSUM) {
      // raw lgkm+barrier (NOT __syncthreads: that drains vmcnt(0) and would
      // kill the in-flight next-tile prefetch in the NT>1 path).
      asm volatile("s_waitcnt lgkmcnt(0)" ::: "memory");
      __builtin_amdgcn_s_barrier();
      if (tid < 256) {
        const f32x4 pp = *(const f32x4*)(fsh + (tid << 2));
        lsum[(n0e >> 8) * 4096L + m0 + tid] = pp[0] + pp[1] + pp[2] + pp[3];
      }
    }
  };

  // prologue: K-iters u=0 (R0-R3) and u=1 (R0-R2); u=1.R3 staged at u=0 ph1.
  STG(pbL, ldb8, 0, 0); STG(paL, lda8, 0, 1);
  STG(pbH, ldb8, 0, 2); STG(paH, lda8, 0, 3);
  asm volatile("s_waitcnt vmcnt(4)" ::: "memory");
  STG(pbL + 64, ldb8, 1, 0); STG(paL + 64, lda8, 1, 1);
  STG(pbH + 64, ldb8, 1, 2);
  asm volatile("s_waitcnt vmcnt(6)" ::: "memory");
  SBAR();

  int kt = 0;            // K-tile index within current output tile
  long boB = 0;          // B-row offset of current output tile (NT>1)
  long n0t = n0;         // current output tile's n0 (epilogue)
  for (int u = 0; u < NU; ++u) {
    const int buf = u & 1;
    // stage-lookahead offsets: (u+1) for A-hi(R3), (u+2) for R0/R1/R2.
    int ka3 = kt + 1; if (ka3 == ntk) ka3 = 0;               // wraps to next tile
    int kt2 = kt + 2; long bt2 = boB;
    if (kt2 >= ntk) { kt2 -= ntk; bt2 += nstep; }
    const long ao3 = (long)ka3 << 6;
    const long ao2 = (long)kt2 << 6;
    const long bo2 = bt2 + ((long)kt2 << 6);

    const bf16* LA = lds + (buf << 15) + (regA << 13) + aoff;
    const bf16* LB = lds + (buf << 15) + (regB << 13) + boff;
    bf16x8 aL[4][2], aH[4][2], bF[4][2];

    // ---- phase 1: read aL (m0-3) + all B; stage (u+1).R3 (other buf) ----
#pragma unroll
    for (int i = 0; i < 4; ++i) {
      aL[i][0] = *(const bf16x8*)(LA + i * 1024 + ok0);
      aL[i][1] = *(const bf16x8*)(LA + i * 1024 + ok1);
    }
#pragma unroll
    for (int j = 0; j < 4; ++j) {
      bF[j][0] = *(const bf16x8*)(LB + j * 1024 + ok0);
      bF[j][1] = *(const bf16x8*)(LB + j * 1024 + ok1);
    }
    if (u + 1 < NU) STG(paH + ao3, lda8, (u + 1) & 1, 3);
    SBAR();
    LGKM0();
    __builtin_amdgcn_s_setprio(1);
    CLUSTER(0, 0, aL);
    __builtin_amdgcn_s_setprio(0);
    SBAR();

    // ---- phase 2: read aH (m4-7); stage (u+2).R0 ----
#pragma unroll
    for (int i = 0; i < 4; ++i) {
      aH[i][0] = *(const bf16x8*)(LA + (4 + i) * 1024 + ok0);
      aH[i][1] = *(const bf16x8*)(LA + (4 + i) * 1024 + ok1);
    }
    if (u + 2 < NU) STG(pbL + bo2, ldb8, buf, 0);
    SBAR();
    LGKM0();
    __builtin_amdgcn_s_setprio(1);
    CLUSTER(4, 0, aH);
    __builtin_amdgcn_s_setprio(0);
    SBAR();

    // ---- phase 3: stage (u+2).R1 ----
    if (u + 2 < NU) STG(paL + ao2, lda8, buf, 1);
    SBAR();
    __builtin_amdgcn_s_setprio(1);
    CLUSTER(0, 2, aL);
    __builtin_amdgcn_s_setprio(0);
    SBAR();

    // ---- phase 4: stage (u+2).R2; counted vmcnt (drain only at tail) ----
    if (u + 2 < NU) STG(pbH + bo2, ldb8, buf, 2);
    SBAR();
    __builtin_amdgcn_s_setprio(1);
    CLUSTER(4, 2, aH);
    __builtin_amdgcn_s_setprio(0);
    if (u + 2 < NU) asm volatile("s_waitcnt vmcnt(6)" ::: "memory");
    else            asm volatile("s_waitcnt vmcnt(0)" ::: "memory");
    SBAR();

    // ---- output-tile boundary (NT>1): epilogue + acc reset, pipeline flows on
    ++kt;
    if constexpr (NT > 1) {
      if (kt == ntk) {
        kt = 0; boB += nstep;
        epi(n0t);
        n0t += 256;
#pragma unroll
        for (int i = 0; i < 8; ++i)
#pragma unroll
          for (int j = 0; j < 4; ++j) acc[i][j] = zero;
      }
    }
  }

  if constexpr (NT == 1) epi(n0);
}

extern "C" void kernel_launch(void* const* d_in, const int* in_sizes, int n_in,
                              void* d_out, int out_size, void* d_ws, size_t ws_size,
                              hipStream_t stream)
{
  (void)in_sizes; (void)n_in; (void)out_size;
  char* ws = (char*)d_ws;

  if (ws_size < (size_t)(OFF_ATT + ATT_B)) return;  // out stays 0 -> 0.157 diagnostic
  const size_t avail = ws_size - (size_t)OFF_ATT;
  int group = (int)(avail / (size_t)ATT_B);
  group = group >= 4 ? 4 : (group >= 2 ? 2 : 1);

  bf16*  q    = (bf16*)(ws + OFF_Q);    // later: yT slots / y' flat
  bf16*  k    = (bf16*)(ws + OFF_K);
  bf16*  vT2  = (bf16*)(ws + OFF_VT);   // [768][16384]
  bf16*  Wn   = (bf16*)(ws + OFF_W);    // 4 x 589824
  bf16*  bn   = (bf16*)(ws + OFF_B);    // 4 x 768
  int*   flg  = (int*)(ws + OFF_FLAG);
  bf16*  att  = (bf16*)(ws + OFF_ATT);
  bf16*  xn   = att;                    // alias: dead before att is written
  // lsum2 [4 batches][16 colgrp][4096] f32 = 1MB in the dead Wq region
  // (dead after the projections; < Wq's 1.15MB, Wk/Wv/Wc untouched).
  float* lsum2 = (float*)(ws + OFF_W);

  dim3 blk(256, 1, 1), blk2(512, 1, 1);
  const float qs = 0.03608439182435161f;  // 768^-0.5

  // 1) fused sniff + normalize (x, 4xW, 4xb): ONE launch.
  normalize_all<<<7300, blk, 0, stream>>>(d_in[0],
                                          d_in[1], d_in[2], d_in[3], d_in[4],
                                          d_in[5], d_in[6], d_in[7], d_in[8],
                                          xn, Wn, bn, flg);

  // 2) QKV projections, SEPARATE launches (fusion regresses EXPSUM, proven 3x).
  dim3 gproj(3, 64, 1);
  gemm256<M_PLAIN><<<gproj, blk2, 0, stream>>>(xn, 768, 0, Wn + 0 * 589824L, 768, 0,
                                               q, 768, 0, 768, bn + 0, qs, nullptr, nullptr);
  gemm256<M_PLAIN><<<gproj, blk2, 0, stream>>>(xn, 768, 0, Wn + 1 * 589824L, 768, 0,
                                               k, 768, 0, 768, bn + 768, 1.f, nullptr, nullptr);
  gemm256<M_TRANSC><<<gproj, blk2, 0, stream>>>(xn, 768, 0, Wn + 2 * 589824L, 768, 0,
                                                vT2, 16384, 0, 768, bn + 1536, 1.f, nullptr, nullptr);

  // 3) Attention: P = exp(q@k^T) w/ partial row-sums; yT = vT@P^T / l.
  if (group == 4) {
    // persistent NT=4 EXPSUM: 256 blocks (1/CU), 4 tiles each, z internal.
    gemm256<M_EXPSUM, 4><<<dim3(256, 1, 1), blk2, 0, stream>>>(
        q, 768, SD, k, 768, SD, att, 4096, 16777216L, 768, nullptr, 1.f,
        nullptr, lsum2);
    dim3 gpv(16, 3, 4);
    gemm256<M_DIVL><<<gpv, blk2, 0, stream>>>(vT2, 16384, 4096L,
                                              att, 4096, 16777216L,
                                              q, 4096, SD, 4096, nullptr, 1.f,
                                              nullptr, lsum2);
  } else {
    for (int g = 0; g < 4; g += group) {
      dim3 gs(16, 16, group);
      gemm256<M_EXPSUM><<<gs, blk2, 0, stream>>>(q + g * SD, 768, SD, k + g * SD, 768, SD,
                                                 att, 4096, 16777216L, 768, nullptr, 1.f,
                                                 nullptr, lsum2 + g * 65536L);
      dim3 gpv(16, 3, group);
      gemm256<M_DIVL><<<gpv, blk2, 0, stream>>>(vT2 + g * 4096L, 16384, 4096L,
                                                att, 4096, 16777216L,
                                                q + g * SD, 4096, SD, 4096, nullptr, 1.f,
                                                nullptr, lsum2 + g * 65536L);
    }
  }

  // 4) out = y' @ Wc^T + bc  (q region flat == y' [16384][768]); fp32 out per flag.
  dim3 gout(3, 64, 1);
  gemm256<M_PLAIN><<<gout, blk2, 0, stream>>>(q, 768, 0, Wn + 3 * 589824L, 768, 0,
                                              d_out, 768, 0, 768, bn + 2304, 1.f, flg, nullptr);
}